// Round 1
// baseline (1038.131 us; speedup 1.0000x reference)
//
#include <hip/hip_runtime.h>
#include <stdint.h>

#define B_   8
#define L_   2048
#define D_   256
#define H_   256

typedef short bf16x8 __attribute__((ext_vector_type(8)));
typedef float f32x4  __attribute__((ext_vector_type(4)));
typedef float f32x4v __attribute__((ext_vector_type(4)));

#define MFMA(a,b,c) __builtin_amdgcn_mfma_f32_16x16x32_bf16(a,b,c,0,0,0)

__device__ __forceinline__ unsigned short f2bf(float f){
  union { float f; unsigned int u; } c; c.f = f;
  unsigned int u = c.u;
  unsigned int r = (u + 0x7fffu + ((u >> 16) & 1u)) >> 16;
  return (unsigned short)r;
}

// ---------------- weight norm: w[h,:] = g[h] * v[h,:] / ||v[h,:]|| -> bf16
__global__ __launch_bounds__(256) void wnorm_kernel(const float* __restrict__ v,
                                                    const float* __restrict__ g,
                                                    unsigned short* __restrict__ w){
  int h = blockIdx.x;
  int d = threadIdx.x;
  float x = v[h*D_ + d];
  float sq = x*x;
  for (int off = 32; off; off >>= 1) sq += __shfl_down(sq, off, 64);
  __shared__ float red[4];
  int lane = threadIdx.x & 63, wid = threadIdx.x >> 6;
  if (lane == 0) red[wid] = sq;
  __syncthreads();
  float tot = red[0] + red[1] + red[2] + red[3];
  float scale = g[h] / sqrtf(tot);
  w[h*D_ + d] = f2bf(x * scale);
}

// ---------------- transpose+convert: x [B][L][D] f32 -> xT [B][D][L] bf16
__global__ __launch_bounds__(256) void transpose_kernel(const float* __restrict__ x,
                                                        unsigned short* __restrict__ xT){
  __shared__ float tile[32][33];
  int bz = blockIdx.z;
  int l0 = blockIdx.x * 32;
  int d0 = blockIdx.y * 32;
  int tx = threadIdx.x, ty = threadIdx.y; // (32,8)
  const float* xp = x + (size_t)bz * L_ * D_;
  for (int k = 0; k < 4; k++)
    tile[ty + 8*k][tx] = xp[(size_t)(l0 + ty + 8*k) * D_ + d0 + tx];
  __syncthreads();
  unsigned short* op = xT + (size_t)bz * D_ * L_;
  for (int k = 0; k < 4; k++)
    op[(size_t)(d0 + ty + 8*k) * L_ + l0 + tx] = f2bf(tile[tx][ty + 8*k]);
}

// ---------------- hx = bf16(scale * relu(x @ w^T + bias));  x:[M][256] f32, w:[256][256] bf16
__global__ __launch_bounds__(256) void hgemm_kernel(const float* __restrict__ x,
      const unsigned short* __restrict__ w, const float* __restrict__ bias,
      const float* __restrict__ tau_ptr, int apply_tau,
      unsigned short* __restrict__ hx){
  int m0 = blockIdx.x * 64;
  int c0 = blockIdx.y * 64;
  int lane = threadIdx.x & 63, wid = threadIdx.x >> 6;
  int row = m0 + wid*16 + (lane & 15);
  int kb  = (lane >> 4) * 8;
  float scale = apply_tau ? tau_ptr[0] : 1.0f;
  f32x4 acc[4] = {};
  for (int kk = 0; kk < 8; kk++){
    const float* ap = x + (size_t)row * 256 + kk*32 + kb;
    f32x4v a0 = *(const f32x4v*)ap;
    f32x4v a1 = *(const f32x4v*)(ap + 4);
    bf16x8 af;
    af[0]=(short)f2bf(a0[0]); af[1]=(short)f2bf(a0[1]); af[2]=(short)f2bf(a0[2]); af[3]=(short)f2bf(a0[3]);
    af[4]=(short)f2bf(a1[0]); af[5]=(short)f2bf(a1[1]); af[6]=(short)f2bf(a1[2]); af[7]=(short)f2bf(a1[3]);
    for (int n = 0; n < 4; n++){
      int col = c0 + n*16 + (lane & 15);
      bf16x8 bfr = *(const bf16x8*)(w + (size_t)col * 256 + kk*32 + kb);
      acc[n] = MFMA(af, bfr, acc[n]);
    }
  }
  for (int n = 0; n < 4; n++){
    int col = c0 + n*16 + (lane & 15);
    float bv = bias[col];
    for (int r = 0; r < 4; r++){
      int orow = m0 + wid*16 + (lane >> 4)*4 + r;
      float vv = acc[n][r] + bv;
      vv = vv > 0.f ? vv : 0.f;
      hx[(size_t)orow * 256 + col] = f2bf(vv * scale);
    }
  }
}

// ---------------- softmax stats over cols of P = hA @ hB^T (+mask on cols); per row: max,sum
__global__ __launch_bounds__(256) void stats_kernel(const unsigned short* __restrict__ hA,
      const unsigned short* __restrict__ hB, const int* __restrict__ mask,
      float* __restrict__ omax, float* __restrict__ osum){
  int bz = blockIdx.y;
  int i0 = blockIdx.x * 64;
  int lane = threadIdx.x & 63, wid = threadIdx.x >> 6;
  int row = i0 + wid*16 + (lane & 15);
  int kb = (lane >> 4) * 8;
  const unsigned short* hAp = hA + (size_t)bz * L_ * H_;
  const unsigned short* hBp = hB + (size_t)bz * L_ * H_;
  const int* mp = mask + bz * L_;
  bf16x8 af[8];
  for (int kk = 0; kk < 8; kk++)
    af[kk] = *(const bf16x8*)(hAp + (size_t)row * H_ + kk*32 + kb);
  float m_run[4], s_run[4];
  for (int r = 0; r < 4; r++){ m_run[r] = -__builtin_inff(); s_run[r] = 0.f; }
  for (int j0 = 0; j0 < L_; j0 += 32){
    for (int n = 0; n < 2; n++){
      int col = j0 + n*16 + (lane & 15);
      f32x4 acc = {};
      const unsigned short* bp = hBp + (size_t)col * H_ + kb;
      for (int kk = 0; kk < 8; kk++){
        bf16x8 bfr = *(const bf16x8*)(bp + kk*32);
        acc = MFMA(af[kk], bfr, acc);
      }
      float mterm = (mp[col] > 0) ? 0.f : -1e9f;
      for (int r = 0; r < 4; r++){
        float xv = acc[r] + mterm;
        float mn = fmaxf(m_run[r], xv);
        s_run[r] = s_run[r] * __expf(m_run[r] - mn) + __expf(xv - mn);
        m_run[r] = mn;
      }
    }
  }
  for (int off = 1; off < 16; off <<= 1){
    for (int r = 0; r < 4; r++){
      float om = __shfl_xor(m_run[r], off, 64);
      float os = __shfl_xor(s_run[r], off, 64);
      float mn = fmaxf(m_run[r], om);
      s_run[r] = s_run[r] * __expf(m_run[r] - mn) + os * __expf(om - mn);
      m_run[r] = mn;
    }
  }
  if ((lane & 15) == 0){
    for (int r = 0; r < 4; r++){
      int orow = i0 + wid*16 + (lane >> 4)*4 + r;
      omax[bz * L_ + orow] = m_run[r];
      osum[bz * L_ + orow] = s_run[r];
    }
  }
}

// ---------------- out[rows][256] = softmax_rows(hA@hB^T + mask) @ V  (V given as vT [D][L] bf16)
__global__ __launch_bounds__(256) void align_kernel(const unsigned short* __restrict__ hA,
      const unsigned short* __restrict__ hB, const unsigned short* __restrict__ vT,
      const int* __restrict__ mask, const float* __restrict__ omax,
      const float* __restrict__ osum, float* __restrict__ out){
  __shared__ __align__(16) unsigned short wtile[4][16][32];
  int bz = blockIdx.y;
  int i0 = blockIdx.x * 64;
  int lane = threadIdx.x & 63, wid = threadIdx.x >> 6;
  int row = i0 + wid*16 + (lane & 15);
  int kb = (lane >> 4) * 8;
  const unsigned short* hAp = hA + (size_t)bz * L_ * H_;
  const unsigned short* hBp = hB + (size_t)bz * L_ * H_;
  const unsigned short* vTp = vT + (size_t)bz * D_ * L_;
  const int* mp = mask + bz * L_;
  bf16x8 af[8];
  for (int kk = 0; kk < 8; kk++)
    af[kk] = *(const bf16x8*)(hAp + (size_t)row * H_ + kk*32 + kb);
  float mrow[4], inv_s[4];
  for (int r = 0; r < 4; r++){
    int orow = i0 + wid*16 + (lane >> 4)*4 + r;
    mrow[r] = omax[bz * L_ + orow];
    inv_s[r] = 1.0f / osum[bz * L_ + orow];
  }
  f32x4 acc[16] = {};
  for (int j0 = 0; j0 < L_; j0 += 32){
    for (int n = 0; n < 2; n++){
      int col = j0 + n*16 + (lane & 15);
      f32x4 accp = {};
      const unsigned short* bp = hBp + (size_t)col * H_ + kb;
      for (int kk = 0; kk < 8; kk++){
        bf16x8 bfr = *(const bf16x8*)(bp + kk*32);
        accp = MFMA(af[kk], bfr, accp);
      }
      float mterm = (mp[col] > 0) ? 0.f : -1e9f;
      for (int r = 0; r < 4; r++){
        float xv = accp[r] + mterm;
        float wv = __expf(xv - mrow[r]) * inv_s[r];
        wtile[wid][(lane >> 4)*4 + r][n*16 + (lane & 15)] = f2bf(wv);
      }
    }
    __syncthreads();
    bf16x8 wf = *(const bf16x8*)(&wtile[wid][lane & 15][kb]);
    for (int n = 0; n < 16; n++){
      int dcol = n*16 + (lane & 15);
      bf16x8 vf = *(const bf16x8*)(vTp + (size_t)dcol * L_ + j0 + kb);
      acc[n] = MFMA(wf, vf, acc[n]);
    }
    __syncthreads();
  }
  for (int n = 0; n < 16; n++){
    int dcol = n*16 + (lane & 15);
    for (int r = 0; r < 4; r++){
      int orow = i0 + wid*16 + (lane >> 4)*4 + r;
      out[((size_t)bz * L_ + orow) * D_ + dcol] = acc[n][r];
    }
  }
}

extern "C" void kernel_launch(void* const* d_in, const int* in_sizes, int n_in,
                              void* d_out, int out_size, void* d_ws, size_t ws_size,
                              hipStream_t stream) {
  const float* a      = (const float*)d_in[0];
  const float* b      = (const float*)d_in[1];
  const int*   mask_a = (const int*)d_in[2];
  const int*   mask_b = (const int*)d_in[3];
  const float* a_v    = (const float*)d_in[4];
  const float* a_g    = (const float*)d_in[5];
  const float* a_bias = (const float*)d_in[6];
  const float* b_v    = (const float*)d_in[7];
  const float* b_g    = (const float*)d_in[8];
  const float* b_bias = (const float*)d_in[9];
  const float* tau    = (const float*)d_in[10];

  float* out_a = (float*)d_out;
  float* out_b = out_a + (size_t)B_ * L_ * D_;

  char* ws = (char*)d_ws;
  const size_t SZ_W  = (size_t)H_ * D_ * 2;        // 128 KB
  const size_t SZ_H  = (size_t)B_ * L_ * H_ * 2;   // 8 MB
  unsigned short* wa = (unsigned short*)(ws);
  unsigned short* wb = (unsigned short*)(ws + SZ_W);
  unsigned short* ha = (unsigned short*)(ws + 2*SZ_W);
  unsigned short* hb = (unsigned short*)(ws + 2*SZ_W + SZ_H);
  unsigned short* aT = (unsigned short*)(ws + 2*SZ_W + 2*SZ_H);
  unsigned short* bT = (unsigned short*)(ws + 2*SZ_W + 3*SZ_H);
  float* rmax = (float*)(ws + 2*SZ_W + 4*SZ_H);
  float* rsum = rmax + B_*L_;
  float* cmax = rsum + B_*L_;
  float* csum = cmax + B_*L_;
  size_t need = 2*SZ_W + 4*SZ_H + 4*(size_t)B_*L_*4;
  if (ws_size < need) return;

  // 1. normalized weights (bf16)
  wnorm_kernel<<<H_, 256, 0, stream>>>(a_v, a_g, wa);
  wnorm_kernel<<<H_, 256, 0, stream>>>(b_v, b_g, wb);

  // 2. transposed bf16 copies of a, b  ([B][D][L])
  {
    dim3 g(L_/32, D_/32, B_), blk(32, 8);
    transpose_kernel<<<g, blk, 0, stream>>>(a, aT);
    transpose_kernel<<<g, blk, 0, stream>>>(b, bT);
  }

  // 3. ha = bf16(tau*relu(a@wa^T + bias)), hb = bf16(relu(b@wb^T + bias))
  {
    dim3 g((B_*L_)/64, H_/64);
    hgemm_kernel<<<g, 256, 0, stream>>>(a, wa, a_bias, tau, 1, ha);
    hgemm_kernel<<<g, 256, 0, stream>>>(b, wb, b_bias, tau, 0, hb);
  }

  // 4. softmax stats: rows of attn (mask_b over j) and rows of attn^T (mask_a over i)
  {
    dim3 g(L_/64, B_);
    stats_kernel<<<g, 256, 0, stream>>>(ha, hb, mask_b, rmax, rsum);
    stats_kernel<<<g, 256, 0, stream>>>(hb, ha, mask_a, cmax, csum);
  }

  // 5. align_a = softmax_j(attn) @ b ; align_b = softmax_i(attn)^T @ a
  {
    dim3 g(L_/64, B_);
    align_kernel<<<g, 256, 0, stream>>>(ha, hb, bT, mask_b, rmax, rsum, out_a);
    align_kernel<<<g, 256, 0, stream>>>(hb, ha, aT, mask_a, cmax, csum, out_b);
  }
}

// Round 2
// 356.095 us; speedup vs baseline: 2.9153x; 2.9153x over previous
//
#include <hip/hip_runtime.h>
#include <stdint.h>

#define B_   8
#define L_   2048
#define D_   256
#define H_   256

typedef short bf16x8 __attribute__((ext_vector_type(8)));
typedef float f32x4  __attribute__((ext_vector_type(4)));

#define MFMA(a,b,c) __builtin_amdgcn_mfma_f32_16x16x32_bf16(a,b,c,0,0,0)

__device__ __forceinline__ unsigned short f2bf(float f){
  union { float f; unsigned int u; } c; c.f = f;
  unsigned int u = c.u;
  unsigned int r = (u + 0x7fffu + ((u >> 16) & 1u)) >> 16;
  return (unsigned short)r;
}

// ---------------- weight norm: w[h,:] = g[h] * v[h,:] / ||v[h,:]|| -> bf16
__global__ __launch_bounds__(256) void wnorm_kernel(const float* __restrict__ v,
                                                    const float* __restrict__ g,
                                                    unsigned short* __restrict__ w){
  int h = blockIdx.x;
  int d = threadIdx.x;
  float x = v[h*D_ + d];
  float sq = x*x;
  for (int off = 32; off; off >>= 1) sq += __shfl_down(sq, off, 64);
  __shared__ float red[4];
  int lane = threadIdx.x & 63, wid = threadIdx.x >> 6;
  if (lane == 0) red[wid] = sq;
  __syncthreads();
  float tot = red[0] + red[1] + red[2] + red[3];
  float scale = g[h] / sqrtf(tot);
  w[h*D_ + d] = f2bf(x * scale);
}

// ---------------- transpose+convert: x [B][L][D] f32 -> xT [B][D][L] bf16
__global__ __launch_bounds__(256) void transpose_kernel(const float* __restrict__ x,
                                                        unsigned short* __restrict__ xT){
  __shared__ float tile[32][33];
  int bz = blockIdx.z;
  int l0 = blockIdx.x * 32;
  int d0 = blockIdx.y * 32;
  int tx = threadIdx.x, ty = threadIdx.y; // (32,8)
  const float* xp = x + (size_t)bz * L_ * D_;
  for (int k = 0; k < 4; k++)
    tile[ty + 8*k][tx] = xp[(size_t)(l0 + ty + 8*k) * D_ + d0 + tx];
  __syncthreads();
  unsigned short* op = xT + (size_t)bz * D_ * L_;
  for (int k = 0; k < 4; k++)
    op[(size_t)(d0 + ty + 8*k) * L_ + l0 + tx] = f2bf(tile[tx][ty + 8*k]);
}

// ---------------- hx = bf16(scale * relu(x @ w^T + bias));  x:[M][256] f32, w:[256][256] bf16
__global__ __launch_bounds__(256) void hgemm_kernel(const float* __restrict__ x,
      const unsigned short* __restrict__ w, const float* __restrict__ bias,
      const float* __restrict__ tau_ptr, int apply_tau,
      unsigned short* __restrict__ hx){
  int m0 = blockIdx.x * 64;
  int c0 = blockIdx.y * 64;
  int lane = threadIdx.x & 63, wid = threadIdx.x >> 6;
  int row = m0 + wid*16 + (lane & 15);
  int kb  = (lane >> 4) * 8;
  float scale = apply_tau ? tau_ptr[0] : 1.0f;
  f32x4 acc[4] = {};
  for (int kk = 0; kk < 8; kk++){
    const float* ap = x + (size_t)row * 256 + kk*32 + kb;
    f32x4 a0 = *(const f32x4*)ap;
    f32x4 a1 = *(const f32x4*)(ap + 4);
    bf16x8 af;
    af[0]=(short)f2bf(a0[0]); af[1]=(short)f2bf(a0[1]); af[2]=(short)f2bf(a0[2]); af[3]=(short)f2bf(a0[3]);
    af[4]=(short)f2bf(a1[0]); af[5]=(short)f2bf(a1[1]); af[6]=(short)f2bf(a1[2]); af[7]=(short)f2bf(a1[3]);
    for (int n = 0; n < 4; n++){
      int col = c0 + n*16 + (lane & 15);
      bf16x8 bfr = *(const bf16x8*)(w + (size_t)col * 256 + kk*32 + kb);
      acc[n] = MFMA(af, bfr, acc[n]);
    }
  }
  for (int n = 0; n < 4; n++){
    int col = c0 + n*16 + (lane & 15);
    float bv = bias[col];
    for (int r = 0; r < 4; r++){
      int orow = m0 + wid*16 + (lane >> 4)*4 + r;
      float vv = acc[n][r] + bv;
      vv = vv > 0.f ? vv : 0.f;
      hx[(size_t)orow * 256 + col] = f2bf(vv * scale);
    }
  }
}

// ---------------- fused flash alignment:
// dir 0: out_a[i,:] = softmax_j(ha@hb^T + maskb_j) @ b     (vT = bT)
// dir 1: out_b[j,:] = softmax_i(hb@ha^T + maska_i) @ a     (vT = aT)
// Block: 32 output rows, 2 waves; wave w handles j in [w*1024, w*1024+1024),
// online softmax w/ defer-rescale, 2-way merge at the end via LDS.
__global__ __launch_bounds__(128, 2) void flash_kernel(
    const unsigned short* __restrict__ ha, const unsigned short* __restrict__ hb,
    const unsigned short* __restrict__ aT, const unsigned short* __restrict__ bT,
    const int* __restrict__ mask_a, const int* __restrict__ mask_b,
    float* __restrict__ out)
{
  __shared__ __align__(16) unsigned short wtile[2][32][32];
  __shared__ float mstat[2][32];
  __shared__ float sstat[2][32];
  __shared__ float accbuf[32][256];

  const int dir = blockIdx.z;
  const int bz  = blockIdx.y;
  const int i0  = blockIdx.x * 32;
  const int lane = threadIdx.x & 63;
  const int wid  = threadIdx.x >> 6;
  const int p = lane & 15, q = lane >> 4;
  const int kb = q * 8;

  const unsigned short* hA = dir ? hb : ha;
  const unsigned short* hB = dir ? ha : hb;
  const unsigned short* vT = dir ? aT : bT;
  const int* mask = dir ? mask_a : mask_b;
  float* outp = out + ((size_t)dir * B_ + bz) * L_ * D_;

  const unsigned short* hAp = hA + (size_t)bz * L_ * H_;
  const unsigned short* hBp = hB + (size_t)bz * L_ * H_;
  const unsigned short* vTp = vT + (size_t)bz * D_ * L_;
  const int* mp = mask + bz * L_;

  bf16x8 af[2][8];
  #pragma unroll
  for (int G = 0; G < 2; ++G)
    #pragma unroll
    for (int kk = 0; kk < 8; ++kk)
      af[G][kk] = *(const bf16x8*)(hAp + (size_t)(i0 + G*16 + p) * H_ + kk*32 + kb);

  f32x4 acc[2][16];
  #pragma unroll
  for (int G = 0; G < 2; ++G)
    #pragma unroll
    for (int n = 0; n < 16; ++n)
      acc[G][n] = (f32x4){0.f, 0.f, 0.f, 0.f};

  float m_run[2][4], s_run[2][4];
  #pragma unroll
  for (int G = 0; G < 2; ++G)
    #pragma unroll
    for (int r = 0; r < 4; ++r){ m_run[G][r] = -1e30f; s_run[G][r] = 0.f; }

  const int jbase = wid * (L_ / 2);
  for (int jt = 0; jt < (L_/2)/32; ++jt){
    const int j0 = jbase + jt*32;
    // ---- P = hA[i0:i0+32] @ hB[j0:j0+32]^T  (K = 256)
    f32x4 accp[2][2];
    #pragma unroll
    for (int G = 0; G < 2; ++G)
      #pragma unroll
      for (int n = 0; n < 2; ++n)
        accp[G][n] = (f32x4){0.f, 0.f, 0.f, 0.f};
    #pragma unroll
    for (int kk = 0; kk < 8; ++kk){
      bf16x8 b0 = *(const bf16x8*)(hBp + (size_t)(j0 + p)      * H_ + kk*32 + kb);
      bf16x8 b1 = *(const bf16x8*)(hBp + (size_t)(j0 + 16 + p) * H_ + kk*32 + kb);
      accp[0][0] = MFMA(af[0][kk], b0, accp[0][0]);
      accp[1][0] = MFMA(af[1][kk], b0, accp[1][0]);
      accp[0][1] = MFMA(af[0][kk], b1, accp[0][1]);
      accp[1][1] = MFMA(af[1][kk], b1, accp[1][1]);
    }
    // ---- mask + tile max
    float mt0 = (mp[j0 + p]      > 0) ? 0.f : -1e9f;
    float mt1 = (mp[j0 + 16 + p] > 0) ? 0.f : -1e9f;
    float tmax[2][4];
    #pragma unroll
    for (int G = 0; G < 2; ++G)
      #pragma unroll
      for (int r = 0; r < 4; ++r){
        accp[G][0][r] += mt0;
        accp[G][1][r] += mt1;
        tmax[G][r] = fmaxf(accp[G][0][r], accp[G][1][r]);
      }
    #pragma unroll
    for (int off = 1; off < 16; off <<= 1)
      #pragma unroll
      for (int G = 0; G < 2; ++G)
        #pragma unroll
        for (int r = 0; r < 4; ++r)
          tmax[G][r] = fmaxf(tmax[G][r], __shfl_xor(tmax[G][r], off, 64));
    // ---- online update with defer-rescale (THR = 8)
    int need = 0;
    #pragma unroll
    for (int G = 0; G < 2; ++G)
      #pragma unroll
      for (int r = 0; r < 4; ++r)
        need |= (tmax[G][r] > m_run[G][r] + 8.f) ? 1 : 0;
    if (__any(need)){
      float fsc[2][4];
      #pragma unroll
      for (int G = 0; G < 2; ++G)
        #pragma unroll
        for (int r = 0; r < 4; ++r){
          float mn = fmaxf(m_run[G][r], tmax[G][r]);
          fsc[G][r] = __expf(m_run[G][r] - mn);
          s_run[G][r] *= fsc[G][r];
          m_run[G][r] = mn;
        }
      #pragma unroll
      for (int G = 0; G < 2; ++G)
        #pragma unroll
        for (int n = 0; n < 16; ++n)
          #pragma unroll
          for (int r = 0; r < 4; ++r)
            acc[G][n][r] *= fsc[G][r];
    }
    // ---- weights -> bf16 -> LDS (per-wave tile, no barrier needed)
    #pragma unroll
    for (int G = 0; G < 2; ++G)
      #pragma unroll
      for (int n = 0; n < 2; ++n)
        #pragma unroll
        for (int r = 0; r < 4; ++r){
          float w = __expf(accp[G][n][r] - m_run[G][r]);
          s_run[G][r] += w;
          wtile[wid][G*16 + q*4 + r][n*16 + p] = f2bf(w);
        }
    asm volatile("s_waitcnt lgkmcnt(0)" ::: "memory");
    bf16x8 wf0 = *(const bf16x8*)(&wtile[wid][p][kb]);
    bf16x8 wf1 = *(const bf16x8*)(&wtile[wid][16 + p][kb]);
    // ---- PV: acc += W @ V  (V as vT [D][L])
    #pragma unroll
    for (int n = 0; n < 16; ++n){
      bf16x8 vf = *(const bf16x8*)(vTp + (size_t)(n*16 + p) * L_ + j0 + kb);
      acc[0][n] = MFMA(wf0, vf, acc[0][n]);
      acc[1][n] = MFMA(wf1, vf, acc[1][n]);
    }
  }

  // ---- reduce s over the 16 col-lanes
  #pragma unroll
  for (int off = 1; off < 16; off <<= 1)
    #pragma unroll
    for (int G = 0; G < 2; ++G)
      #pragma unroll
      for (int r = 0; r < 4; ++r)
        s_run[G][r] += __shfl_xor(s_run[G][r], off, 64);

  // ---- 2-way cross-wave merge
  if (p == 0){
    #pragma unroll
    for (int G = 0; G < 2; ++G)
      #pragma unroll
      for (int r = 0; r < 4; ++r){
        mstat[wid][G*16 + q*4 + r] = m_run[G][r];
        sstat[wid][G*16 + q*4 + r] = s_run[G][r];
      }
  }
  __syncthreads();
  float fac[2][4], invS[2][4];
  const int ow = wid ^ 1;
  #pragma unroll
  for (int G = 0; G < 2; ++G)
    #pragma unroll
    for (int r = 0; r < 4; ++r){
      int row = G*16 + q*4 + r;
      float mo = mstat[ow][row], so = sstat[ow][row];
      float M = fmaxf(m_run[G][r], mo);
      fac[G][r] = __expf(m_run[G][r] - M);
      float S = s_run[G][r] * fac[G][r] + so * __expf(mo - M);
      invS[G][r] = 1.0f / S;
    }
  if (wid == 1){
    #pragma unroll
    for (int G = 0; G < 2; ++G)
      #pragma unroll
      for (int n = 0; n < 16; ++n)
        #pragma unroll
        for (int r = 0; r < 4; ++r)
          accbuf[G*16 + q*4 + r][n*16 + p] = acc[G][n][r] * fac[G][r];
  }
  __syncthreads();
  if (wid == 0){
    #pragma unroll
    for (int G = 0; G < 2; ++G)
      #pragma unroll
      for (int n = 0; n < 16; ++n)
        #pragma unroll
        for (int r = 0; r < 4; ++r){
          int row = G*16 + q*4 + r, col = n*16 + p;
          outp[(size_t)(i0 + row) * D_ + col] =
              (acc[G][n][r] * fac[G][r] + accbuf[row][col]) * invS[G][r];
        }
  }
}

extern "C" void kernel_launch(void* const* d_in, const int* in_sizes, int n_in,
                              void* d_out, int out_size, void* d_ws, size_t ws_size,
                              hipStream_t stream) {
  const float* a      = (const float*)d_in[0];
  const float* b      = (const float*)d_in[1];
  const int*   mask_a = (const int*)d_in[2];
  const int*   mask_b = (const int*)d_in[3];
  const float* a_v    = (const float*)d_in[4];
  const float* a_g    = (const float*)d_in[5];
  const float* a_bias = (const float*)d_in[6];
  const float* b_v    = (const float*)d_in[7];
  const float* b_g    = (const float*)d_in[8];
  const float* b_bias = (const float*)d_in[9];
  const float* tau    = (const float*)d_in[10];

  float* out = (float*)d_out;

  char* ws = (char*)d_ws;
  const size_t SZ_W  = (size_t)H_ * D_ * 2;        // 128 KB
  const size_t SZ_H  = (size_t)B_ * L_ * H_ * 2;   // 8 MB
  unsigned short* wa = (unsigned short*)(ws);
  unsigned short* wb = (unsigned short*)(ws + SZ_W);
  unsigned short* ha = (unsigned short*)(ws + 2*SZ_W);
  unsigned short* hb = (unsigned short*)(ws + 2*SZ_W + SZ_H);
  unsigned short* aT = (unsigned short*)(ws + 2*SZ_W + 2*SZ_H);
  unsigned short* bT = (unsigned short*)(ws + 2*SZ_W + 3*SZ_H);
  size_t need = 2*SZ_W + 4*SZ_H;
  if (ws_size < need) return;

  // 1. normalized weights (bf16)
  wnorm_kernel<<<H_, 256, 0, stream>>>(a_v, a_g, wa);
  wnorm_kernel<<<H_, 256, 0, stream>>>(b_v, b_g, wb);

  // 2. transposed bf16 copies of a, b  ([B][D][L])
  {
    dim3 g(L_/32, D_/32, B_), blk(32, 8);
    transpose_kernel<<<g, blk, 0, stream>>>(a, aT);
    transpose_kernel<<<g, blk, 0, stream>>>(b, bT);
  }

  // 3. ha = bf16(tau*relu(a@wa^T + bias)), hb = bf16(relu(b@wb^T + bias))
  {
    dim3 g((B_*L_)/64, H_/64);
    hgemm_kernel<<<g, 256, 0, stream>>>(a, wa, a_bias, tau, 1, ha);
    hgemm_kernel<<<g, 256, 0, stream>>>(b, wb, b_bias, tau, 0, hb);
  }

  // 4. fused flash alignment, both directions in one launch
  {
    dim3 g(L_/32, B_, 2);
    flash_kernel<<<g, 128, 0, stream>>>(ha, hb, aT, bT, mask_a, mask_b, out);
  }
}